// Round 8
// baseline (604.587 us; speedup 1.0000x reference)
//
#include <hip/hip_runtime.h>
#include <stdint.h>

#define TS 2048
#define CD 128
#define NB 8
#define NROWS (NB*TS)          // 16384
#define RPB 8                  // rows per block in projection kernels
#define SCALE 0.08838834764831845f  // 1/sqrt(128)
#define JSPLIT 3

// async global->LDS, 16 B per lane, dest = wave-uniform base + lane*16
typedef const __attribute__((address_space(1))) void* gas_cptr;
typedef __attribute__((address_space(3))) void* las_ptr;
__device__ __forceinline__ void async16(const void* g, void* l) {
    __builtin_amdgcn_global_load_lds((gas_cptr)g, (las_ptr)l, 16, 0, 0);
}

// ---- Kernel 1: Q = E@Wq^T, K = E@Wk^T (fp32), 8 rows per block ----
__global__ __launch_bounds__(128) void proj_qk(
    const float* __restrict__ E, const float* __restrict__ Wq,
    const float* __restrict__ Wk, float* __restrict__ Q, float* __restrict__ K)
{
    const int r0 = blockIdx.x * RPB, t = threadIdx.x;
    __shared__ float e[RPB][CD];
    {
        const float4* src = (const float4*)(E + (size_t)r0*CD);
        float4* dst = (float4*)&e[0][0];
        dst[t] = src[t];
        dst[t + 128] = src[t + 128];
    }
    __syncthreads();
    const float* wq = Wq + (size_t)t*CD;
    const float* wk = Wk + (size_t)t*CD;
    float aq[RPB], ak[RPB];
    #pragma unroll
    for (int i = 0; i < RPB; i++) { aq[i] = 0.f; ak[i] = 0.f; }
    #pragma unroll
    for (int c = 0; c < CD; c += 4) {
        float4 a = *(const float4*)(wq + c);
        float4 b = *(const float4*)(wk + c);
        #pragma unroll
        for (int i = 0; i < RPB; i++) {
            float e0 = e[i][c+0], e1 = e[i][c+1], e2 = e[i][c+2], e3 = e[i][c+3];
            aq[i] += a.x*e0 + a.y*e1 + a.z*e2 + a.w*e3;
            ak[i] += b.x*e0 + b.y*e1 + b.z*e2 + b.w*e3;
        }
    }
    #pragma unroll
    for (int i = 0; i < RPB; i++) {
        Q[(size_t)(r0+i)*CD + t] = aq[i];
        K[(size_t)(r0+i)*CD + t] = ak[i];
    }
}

// ---- Kernel 2: 64x(688|672) scores per block, async-LDS pipelined ----
// grid 768 = 8n x 32qt x 3sp -> exactly 3 blocks/CU, single phase.
// LDS: sQ dbuf 2x16KB (c-halves, staged once) + sK dbuf 2x16KB = 64 KB.
// 24 chunks (3 tiles x 8), one barrier per chunk; K chunk g+1 issued at
// iter g start via global_load_lds, drained by iter g's syncthreads.
__global__ __launch_bounds__(256, 3) void scores_top3(
    const float* __restrict__ Q, const float* __restrict__ K, float* __restrict__ SPL)
{
    const int b  = blockIdx.x;
    const int n  = b / 96;
    const int r  = b - n*96;
    const int qt = r / 3;
    const int sp = r - qt*3;
    const int q0 = qt * 64;
    const int js = (sp == 0) ? 0 : (sp == 1) ? 688 : 1376;
    const int je = (sp == 0) ? 688 : (sp == 1) ? 1376 : 2048;
    const float* Kb = K + (size_t)n*TS*CD;
    const float* Qb = Q + ((size_t)n*TS + q0)*CD;
    const int tid = threadIdx.x;
    const int tj = tid & 31, tq = tid >> 5;     // row group tq: rows tq*8..+7
    const int wv = tid >> 6, ln = tid & 63;     // wave id, lane id

    __shared__ float4 sQ[2*1024];   // [qb=ch][64 rows][16 f4] (64-col half)
    __shared__ float4 sK[2*1024];   // [kb][4 c4-groups][256 rows]

    float acc[8][8];
    #pragma unroll
    for (int i = 0; i < 8; i++)
        #pragma unroll
        for (int u = 0; u < 8; u++) acc[i][u] = 0.f;

    float t0v[8], t1v[8], t2v[8];
    int   t0i[8], t1i[8], t2i[8];
    #pragma unroll
    for (int i = 0; i < 8; i++) {
        t0v[i] = t1v[i] = t2v[i] = -3e38f;
        t0i[i] = t1i[i] = t2i[i] = 0x7fffffff;
    }

    // ---- staging helpers (inline) ----
    // stage Q half ch into buffer qb (4 issues/thread, 16 KB)
    #define ISSUE_Q(qb, ch)                                                    \
        _Pragma("unroll")                                                      \
        for (int i_ = 0; i_ < 4; i_++) {                                       \
            int f_ = tid + 256*i_;                                             \
            int row_ = f_ >> 4, c4_ = f_ & 15;                                 \
            async16(Qb + (size_t)row_*CD + (ch)*64 + c4_*4,                    \
                    (void*)(sQ + (qb)*1024 + 256*i_ + 64*wv));                 \
        }
    // stage K chunk g (16 c) into buffer g&1; wave wv stages c4-group wv
    #define ISSUE_K(g)                                                         \
        {                                                                      \
            int tile_ = (g) >> 3;                                              \
            int cbase_ = ((g) & 7) * 16;                                       \
            int j0t_ = js + tile_*256;                                         \
            _Pragma("unroll")                                                  \
            for (int s_ = 0; s_ < 4; s_++) {                                   \
                int j_ = j0t_ + ln + 64*s_;                                    \
                if (j_ > TS-1) j_ = TS-1;                                      \
                async16(Kb + (size_t)j_*CD + cbase_ + wv*4,                    \
                        (void*)(sK + ((g)&1)*1024 + wv*256 + 64*s_));          \
            }                                                                  \
        }

    ISSUE_Q(0, 0);
    ISSUE_K(0);
    __syncthreads();          // drains Qh0 + K chunk 0
    ISSUE_Q(1, 1);            // in flight during g=0, drained at g=0 barrier

    #pragma unroll 1
    for (int g = 0; g < 24; g++) {
        if (g + 1 < 24) ISSUE_K(g + 1);
        {   // compute chunk g
            const int ch  = (g >> 2) & 1;
            const int ccl = g & 3;
            const float4* kfp = sK + (g & 1)*1024;
            const float4* qfp = sQ + ch*1024 + (size_t)(tq*8)*16 + ccl*4;
            #pragma unroll
            for (int c4 = 0; c4 < 4; c4++) {
                float4 kf[8];
                #pragma unroll
                for (int u = 0; u < 8; u++) kf[u] = kfp[c4*256 + tj + 32*u];
                #pragma unroll
                for (int i = 0; i < 8; i++) {
                    float4 qf = qfp[(size_t)i*16 + c4];
                    #pragma unroll
                    for (int u = 0; u < 8; u++) {
                        acc[i][u] = __builtin_fmaf(qf.x, kf[u].x, acc[i][u]);
                        acc[i][u] = __builtin_fmaf(qf.y, kf[u].y, acc[i][u]);
                        acc[i][u] = __builtin_fmaf(qf.z, kf[u].z, acc[i][u]);
                        acc[i][u] = __builtin_fmaf(qf.w, kf[u].w, acc[i][u]);
                    }
                }
            }
        }
        if ((g & 7) == 7) {   // end of tile: fold acc into top-3, reset
            const int j0t = js + (g >> 3)*256;
            #pragma unroll
            for (int i = 0; i < 8; i++) {
                #pragma unroll
                for (int u = 0; u < 8; u++) {
                    float v = acc[i][u];
                    int jg = j0t + tj + 32*u;
                    if (jg < je && v > t2v[i]) {
                        if (v > t0v[i]) {
                            t2v[i]=t1v[i]; t2i[i]=t1i[i];
                            t1v[i]=t0v[i]; t1i[i]=t0i[i];
                            t0v[i]=v;      t0i[i]=jg;
                        } else if (v > t1v[i]) {
                            t2v[i]=t1v[i]; t2i[i]=t1i[i];
                            t1v[i]=v;      t1i[i]=jg;
                        } else {
                            t2v[i]=v;      t2i[i]=jg;
                        }
                    }
                    acc[i][u] = 0.f;
                }
            }
        }
        __syncthreads();
    }

    // butterfly merge across the 32 lanes (tj) of each half-wave
    #pragma unroll
    for (int m = 16; m >= 1; m >>= 1) {
        #pragma unroll
        for (int i = 0; i < 8; i++) {
            float ov[3]; int oi[3];
            ov[0] = __shfl_xor(t0v[i], m); oi[0] = __shfl_xor(t0i[i], m);
            ov[1] = __shfl_xor(t1v[i], m); oi[1] = __shfl_xor(t1i[i], m);
            ov[2] = __shfl_xor(t2v[i], m); oi[2] = __shfl_xor(t2i[i], m);
            #pragma unroll
            for (int k = 0; k < 3; k++) {
                float v = ov[k]; int id = oi[k];
                bool g2 = (v > t2v[i]) || (v == t2v[i] && id < t2i[i]);
                if (g2) {
                    bool g0 = (v > t0v[i]) || (v == t0v[i] && id < t0i[i]);
                    bool g1 = (v > t1v[i]) || (v == t1v[i] && id < t1i[i]);
                    if (g0)      { t2v[i]=t1v[i];t2i[i]=t1i[i]; t1v[i]=t0v[i];t1i[i]=t0i[i]; t0v[i]=v;t0i[i]=id; }
                    else if (g1) { t2v[i]=t1v[i];t2i[i]=t1i[i]; t1v[i]=v;t1i[i]=id; }
                    else         { t2v[i]=v;t2i[i]=id; }
                }
            }
        }
    }
    if (tj == 0) {
        #pragma unroll
        for (int i = 0; i < 8; i++) {
            const int row = n*TS + q0 + tq*8 + i;
            float4* dst = (float4*)(SPL + ((size_t)row*JSPLIT + sp)*8);
            dst[0] = make_float4(t0v[i], __int_as_float(t0i[i]),
                                 t1v[i], __int_as_float(t1i[i]));
            dst[1] = make_float4(t2v[i], __int_as_float(t2i[i]), 0.f, 0.f);
        }
    }
    #undef ISSUE_Q
    #undef ISSUE_K
}

// ---- Kernel 3: fused split-merge + softmax + dense attention write ----
// 512 blocks x 32 rows: threads 0..31 merge 9 candidates -> TOP + LDS,
// then all 256 threads stream 32 dense rows (64 KB/block).
__global__ __launch_bounds__(256) void finalize_attn(
    const float* __restrict__ SPL, float* __restrict__ TOP, float* __restrict__ A)
{
    const int t = threadIdx.x;
    const int r0 = blockIdx.x * 32;
    __shared__ float pr[32][8];
    if (t < 32) {
        const int row = r0 + t;
        const float* s = SPL + (size_t)row*JSPLIT*8;
        float b0v=-3e38f, b1v=-3e38f, b2v=-3e38f;
        int   b0i=0x7fffffff, b1i=0x7fffffff, b2i=0x7fffffff;
        #pragma unroll
        for (int sp = 0; sp < JSPLIT; sp++) {
            #pragma unroll
            for (int k = 0; k < 3; k++) {
                float v = s[sp*8 + 2*k];
                int  id = __float_as_int(s[sp*8 + 2*k + 1]);
                bool g2 = (v > b2v) || (v == b2v && id < b2i);
                if (g2) {
                    bool g0 = (v > b0v) || (v == b0v && id < b0i);
                    bool g1 = (v > b1v) || (v == b1v && id < b1i);
                    if (g0)      { b2v=b1v;b2i=b1i; b1v=b0v;b1i=b0i; b0v=v;b0i=id; }
                    else if (g1) { b2v=b1v;b2i=b1i; b1v=v;  b1i=id; }
                    else         { b2v=v;  b2i=id; }
                }
            }
        }
        float e1 = __expf((b1v - b0v)*SCALE);
        float e2 = __expf((b2v - b0v)*SCALE);
        float rz = 1.0f / (1.0f + e1 + e2);
        pr[t][0] = rz; pr[t][1] = e1*rz; pr[t][2] = e2*rz;
        int* pi = (int*)&pr[t][4];
        pi[0] = b0i; pi[1] = b1i; pi[2] = b2i;
        float* dtop = TOP + (size_t)row*8;
        dtop[0] = rz; dtop[1] = e1*rz; dtop[2] = e2*rz;
        int* di = (int*)dtop;
        di[4] = b0i; di[5] = b1i; di[6] = b2i;
    }
    __syncthreads();
    const int col0 = t*8;
    #pragma unroll 4
    for (int rr = 0; rr < 32; rr++) {
        float p0 = pr[rr][0], p1 = pr[rr][1], p2 = pr[rr][2];
        const int* pi = (const int*)&pr[rr][4];
        int i0 = pi[0], i1 = pi[1], i2 = pi[2];
        float vals[8];
        #pragma unroll
        for (int u = 0; u < 8; u++) {
            int col = col0 + u;
            float v = 0.f;
            if (col == i0) v = p0;
            if (col == i1) v = p1;
            if (col == i2) v = p2;
            vals[u] = v;
        }
        float4* dst = (float4*)(A + (size_t)(r0+rr)*TS + col0);
        dst[0] = make_float4(vals[0], vals[1], vals[2], vals[3]);
        dst[1] = make_float4(vals[4], vals[5], vals[6], vals[7]);
    }
}

// ---- Kernel 4: out = (sum_k p_k * E[i_k]) @ Wo^T + bo, 8 rows per block ----
__global__ __launch_bounds__(128) void out_proj(
    const float* __restrict__ E, const float* __restrict__ Wo,
    const float* __restrict__ bo, const float* __restrict__ TOP,
    float* __restrict__ OUT)
{
    const int r0 = blockIdx.x * RPB, t = threadIdx.x;
    const int n = r0 >> 11;
    __shared__ float o[RPB][CD];
    #pragma unroll
    for (int i = 0; i < RPB; i++) {
        const float* s = TOP + (size_t)(r0+i)*8;
        const int* si = (const int*)s;
        const float* e0 = E + ((size_t)n*TS + si[4])*CD;
        const float* e1 = E + ((size_t)n*TS + si[5])*CD;
        const float* e2 = E + ((size_t)n*TS + si[6])*CD;
        o[i][t] = s[0]*e0[t] + s[1]*e1[t] + s[2]*e2[t];
    }
    __syncthreads();
    const float* wr = Wo + (size_t)t*CD;
    float acc[RPB];
    float bias = bo[t];
    #pragma unroll
    for (int i = 0; i < RPB; i++) acc[i] = bias;
    #pragma unroll
    for (int c = 0; c < CD; c += 4) {
        float4 a = *(const float4*)(wr + c);
        #pragma unroll
        for (int i = 0; i < RPB; i++)
            acc[i] += a.x*o[i][c+0] + a.y*o[i][c+1] + a.z*o[i][c+2] + a.w*o[i][c+3];
    }
    #pragma unroll
    for (int i = 0; i < RPB; i++)
        OUT[(size_t)(r0+i)*CD + t] = acc[i];
}

extern "C" void kernel_launch(void* const* d_in, const int* in_sizes, int n_in,
                              void* d_out, int out_size, void* d_ws, size_t ws_size,
                              hipStream_t stream)
{
    const float* E  = (const float*)d_in[0];
    // d_in[1] = ac, unused by the forward pass
    const float* Wq = (const float*)d_in[2];
    const float* Wk = (const float*)d_in[3];
    const float* Wo = (const float*)d_in[4];
    const float* bo = (const float*)d_in[5];

    float* Q   = (float*)d_ws;                       // 16384x128 fp32 (8 MB)
    float* K   = Q + (size_t)NROWS*CD;               // 8 MB
    float* TOP = K + (size_t)NROWS*CD;               // 16384x8 fp32 (512 KB)
    float* SPL = TOP + (size_t)NROWS*8;              // 16384x3x8 fp32 (1.5 MB)

    float* OUT = (float*)d_out;                      // [N,T,C] fp32
    float* A   = OUT + (size_t)NROWS*CD;             // [N,1,T,T] fp32

    proj_qk      <<<NROWS/RPB, 128, 0, stream>>>(E, Wq, Wk, Q, K);
    scores_top3  <<<NB*32*JSPLIT, 256, 0, stream>>>(Q, K, SPL);
    finalize_attn<<<NROWS/32,  256, 0, stream>>>(SPL, TOP, A);
    out_proj     <<<NROWS/RPB, 128, 0, stream>>>(E, Wo, bo, TOP, OUT);
}